// Round 4
// baseline (1251.264 us; speedup 1.0000x reference)
//
#include <hip/hip_runtime.h>
#include <string.h>

// Quantum classifier fwd: 14 qubits, batch 4096, 6 StronglyEntanglingLayers.
// Round 4 (= Round 3 scheme, host-built tables):
//  - canonical per-pass GF(2) relabeling: gate masks = top 4 address bits ->
//    contiguous conflict-free LDS reads; scatter on writes with a map chosen
//    so (lane bits 0-3 -> bank pair) is invertible (incl. role/SW term)
//  - packed v_pk_fma_f32 complex math (8 ops/pair instead of 16)
//  - role swaps folded into an XOR of the read base (SW); expectation taken
//    directly from registers after the last pass
//  - tables built on HOST in kernel_launch, passed by value as kernel arg
//    (~2.9 KB kernarg; avoids constexpr step limits that broke Round 3)

#define NQ      14
#define NLAYERS 6
#define NSTATE  16384
#define BLOCK   1024

typedef unsigned u32;
typedef float v2f __attribute__((ext_vector_type(2)));

struct AllTables {
  u32 swlo[24][4];      // per-pass role low-masks (slot-indexed)
  u32 wA[23][10];       // write map: columns for thread bits
  u32 wB[23][16];       // write map: top-part images (gamma-indexed)
  u32 a0[10], b0[16];   // init scatter (= W_0)
  u32 erlo[2], erhi[2]; // expectation sign rows in final layout
  int check;            // 1 = all invariants verified
  int minr4;
};

// ---------------- host-side GF(2) machinery ----------------
namespace qct {

struct GF2 { unsigned short r[NQ]; };
static GF2 gf2_id(){ GF2 m{}; for(int i=0;i<NQ;++i) m.r[i]=(unsigned short)(1u<<i); return m; }
static GF2 gf2_mul(const GF2& A, const GF2& B){
  GF2 C{};
  for(int i=0;i<NQ;++i){ u32 v=0; for(int k=0;k<NQ;++k) if((A.r[i]>>k)&1) v^=B.r[k]; C.r[i]=(unsigned short)v; }
  return C;
}
static GF2 cnotF(int c, int t){
  GF2 F=gf2_id();
  F.r[13-t]=(unsigned short)((1u<<(13-t))|(1u<<(13-c)));
  return F;
}

struct Lin { u32 c[14]; };                       // c[j] = image of e_j
static u32 lapply(const Lin& L, u32 x){ u32 r=0; for(int j=0;j<14;++j) if((x>>j)&1u) r^=L.c[j]; return r; }
static Lin lcompose(const Lin& A, const Lin& B){ Lin R{}; for(int j=0;j<14;++j) R.c[j]=lapply(A,B.c[j]); return R; }
static Lin lident(){ Lin L{}; for(int j=0;j<14;++j) L.c[j]=1u<<j; return L; }
static Lin linverse(const Lin& L){
  u32 rows[14]={0}, inv[14]={0};
  for(int i=0;i<14;++i){ u32 r=0; for(int j=0;j<14;++j) r|=((L.c[j]>>i)&1u)<<j; rows[i]=r; inv[i]=1u<<i; }
  for(int col=0; col<14; ++col){
    int piv=-1;
    for(int i=col;i<14;++i) if((rows[i]>>col)&1u){piv=i;break;}
    if(piv<0) continue;
    u32 tr=rows[col]; rows[col]=rows[piv]; rows[piv]=tr;
    tr=inv[col]; inv[col]=inv[piv]; inv[piv]=tr;
    for(int i=0;i<14;++i) if(i!=col && ((rows[i]>>col)&1u)){ rows[i]^=rows[col]; inv[i]^=inv[col]; }
  }
  Lin R{};
  for(int j=0;j<14;++j){ u32 cc=0; for(int i=0;i<14;++i) cc|=((inv[i]>>j)&1u)<<i; R.c[j]=cc; }
  return R;
}
static u32 roletrans(const Lin& invS, u32 rho){
  u32 r=0;
  for(int j=0;j<14;++j) r |= (u32)(__builtin_popcount(invS.c[j]&rho)&1) << j;
  return r;
}

struct Span14 { u32 E[14]; u32 EI[14]; };
static void span_init(Span14& S){ for(int i=0;i<14;++i){S.E[i]=0;S.EI[i]=0;} }
static int top14(u32 v){ for(int i=13;i>=0;--i) if((v>>i)&1u) return i; return -1; }
struct Red { u32 v; u32 img; };
static Red span_reduce(const Span14& S, u32 v){
  u32 img=0;
  while(v){
    int b=top14(v);
    if(!S.E[b]) break;
    v^=S.E[b]; img^=S.EI[b];
  }
  Red r; r.v=v; r.img=img; return r;
}
static bool span_add(Span14& S, u32 v, u32 img){
  Red r=span_reduce(S,v);
  if(!r.v) return false;
  int b=top14(r.v);
  S.E[b]=r.v; S.EI[b]=img^r.img;
  return true;
}
static bool span_has(const Span14& S, u32 v){ Red r=span_reduce(S,v); return r.v==0; }

struct WOut { Lin W; int r4; bool okbuild; };

// Build W with W(cin[i]) = cim[i]; criterion: lane-bits(0..3) -> write-address
// low bits, INCLUDING the SW/B term from this-pass role masks `lo`, rank 4.
static WOut build_w(const u32* cin, const u32* cim, int nc, const u32* lo, u32 seed){
  WOut O{}; O.okbuild=true; O.r4=0;
  Span14 SI; span_init(SI);
  Span14 IM; span_init(IM);
  for(int i=0;i<nc;++i){
    if(!span_add(SI,cin[i],cim[i])) O.okbuild=false;
    if(!span_add(IM,cim[i],0))      O.okbuild=false;
  }
  u32 Bcol[4]={0,0,0,0};
  for(int i=0;i<4 && O.okbuild;++i){          // define W on e_{10+i}
    u32 x=1u<<(10+i);
    Red r=span_reduce(SI,x);
    if(r.v==0){ Bcol[i]=r.img; continue; }
    u32 img=0; bool found=false;
    for(int uu=0; uu<14 && !found; ++uu){
      int u=13-(int)(((u32)uu+(seed%14u))%14u);
      u32 cand=1u<<u;
      if(!span_has(IM,cand)){img=cand;found=true;}
    }
    if(!found){O.okbuild=false;break;}
    span_add(SI,x,img); span_add(IM,img,0);
    Bcol[i]=img;
  }
  u32 A4[4]={0,0,0,0};
  for(int j=0;j<4 && O.okbuild;++j){          // criterion bits
    u32 X=0;
    for(int i=0;i<4;++i) if((lo[i]>>j)&1u) X^=Bcol[i];
    u32 x=1u<<j;
    Red r=span_reduce(SI,x);
    if(r.v==0){ A4[j]=r.img^X; continue; }
    u32 img=0; bool found=false;
    for(u32 fm=0; fm<1024u && !found; ++fm){
      u32 cand=(x^X)^((fm^(seed&1023u))<<4);  // fixes only touch bits >=4
      if(cand && !span_has(IM,cand)){img=cand;found=true;}
    }
    if(!found){O.okbuild=false;break;}
    span_add(SI,x,img); span_add(IM,img,0);
    A4[j]=img^X;
  }
  for(int j=4;j<10 && O.okbuild;++j){         // completion
    u32 x=1u<<j;
    if(span_has(SI,x)) continue;
    u32 img=0; bool found=false;
    for(u32 fm=0; fm<4096u && !found; ++fm){
      u32 cand=x^fm;
      if(cand && !span_has(IM,cand)){img=cand;found=true;}
    }
    if(!found){O.okbuild=false;break;}
    span_add(SI,x,img); span_add(IM,img,0);
  }
  if(O.okbuild){
    for(int j=0;j<14;++j){
      Red r=span_reduce(SI,1u<<j);
      if(r.v){O.okbuild=false;break;}
      O.W.c[j]=r.img;
    }
  }
  {
    u32 rr2[4]={A4[0]&15u,A4[1]&15u,A4[2]&15u,A4[3]&15u};
    int rk=0;
    for(int c2=3;c2>=0;--c2){
      int p=-1;
      for(int i2=0;i2<4;++i2) if((rr2[i2]>>c2)&1u){p=i2;break;}
      if(p<0) continue;
      ++rk;
      u32 pv=rr2[p]; rr2[p]=0;
      for(int i2=0;i2<4;++i2) if((rr2[i2]>>c2)&1u) rr2[i2]^=pv;
    }
    O.r4=rk;
  }
  return O;
}

static AllTables make_all(){
  AllTables T; memset(&T, 0, sizeof(T));
  T.check=1; T.minr4=4;
  u32 MU[84]={0}, RHO[84]={0}; u32 er0=0, er1=0;
  {
    GF2 G=gf2_id(), H=gf2_id();
    for(int l=0;l<NLAYERS;++l){
      for(int q=0;q<NQ;++q){
        int idx=l*NQ+q, bit=13-q;
        u32 m=0;
        for(int r=0;r<NQ;++r) m |= ((u32)((H.r[r]>>bit)&1u))<<r;
        MU[idx]=m; RHO[idx]=G.r[bit];
        if(!(__builtin_popcount(m & (u32)G.r[bit])&1)) T.check=0;
      }
      int rr=(l%(NQ-1))+1;
      GF2 C=gf2_id(), Ci=gf2_id();
      for(int q=0;q<NQ;++q){
        GF2 F=cnotF(q,(q+rr)%NQ);
        C=gf2_mul(C,F); Ci=gf2_mul(F,Ci);
      }
      G=gf2_mul(Ci,G); H=gf2_mul(H,C);
    }
    er0=G.r[13]; er1=G.r[12];
  }
  Lin S=lident();
  u32 lo_prev[4]={0,0,0,0};
  for(int b=0;b<24;++b){
    const int l=b>>2, g=b&3;
    const int ng=(g<3)?4:2, q0=(g<3)?4*g:12;
    u32 cin[4]={0,0,0,0}, cim[4]={0,0,0,0}; int nc=0;
    for(int i=0;i<ng;++i){
      cin[nc]=lapply(S,MU[l*NQ+q0+i]);
      cim[nc]=(ng==4)?(1u<<(10+i)):(1u<<(12+i));
      ++nc;
    }
    if(ng==2){
      // free top dims: pick v orthogonal to both roles -> canonical roles
      Lin invS=linverse(S);
      u32 rp0=roletrans(invS,RHO[l*NQ+12]);
      u32 rp1=roletrans(invS,RHO[l*NQ+13]);
      int got=0;
      for(u32 cs=1; cs<16384u && got<2; ++cs){
        u32 v=(cs*2654435761u)&16383u;
        if(!v) continue;
        if(__builtin_popcount(v&rp0)&1) continue;
        if(__builtin_popcount(v&rp1)&1) continue;
        Span14 tmp; span_init(tmp);
        bool ind=true;
        for(int i=0;i<nc;++i) if(!span_add(tmp,cin[i],0)) ind=false;
        if(ind && span_add(tmp,v,0)){ cin[nc]=v; cim[nc]=1u<<(10+got); ++nc; ++got; }
      }
      if(got<2) T.check=0;
    }
    WOut best; memset(&best,0,sizeof(best)); bool haveBest=false;
    for(u32 sd=0; sd<64; ++sd){
      WOut w=build_w(cin,cim,nc,lo_prev, sd*2654435761u + (u32)b*40503u + 1u);
      if(!haveBest || (w.okbuild && !best.okbuild) ||
         (w.okbuild==best.okbuild && w.r4>best.r4)){ best=w; haveBest=true; }
      if(best.okbuild && best.r4==4) break;
    }
    if(!best.okbuild) T.check=0;
    if(best.r4<T.minr4) T.minr4=best.r4;
    if(b==0){
      for(int j=0;j<10;++j) T.a0[j]=best.W.c[j];
      for(int gm=0;gm<16;++gm){ u32 x=0; for(int i=0;i<4;++i) if((gm>>i)&1) x^=best.W.c[10+i]; T.b0[gm]=x; }
    } else {
      for(int j=0;j<10;++j) T.wA[b-1][j]=best.W.c[j];
      for(int gm=0;gm<16;++gm){ u32 x=0; for(int i=0;i<4;++i) if((gm>>i)&1) x^=best.W.c[10+i]; T.wB[b-1][gm]=x; }
    }
    S=lcompose(best.W,S);
    Lin invS2=linverse(S);
    for(int i=0;i<4;++i) T.swlo[b][i]=0;
    for(int i=0;i<ng;++i){
      int gi=l*NQ+q0+i;
      u32 rp=roletrans(invS2,RHO[gi]);
      int slot=(ng==4)?i:(2+i);
      T.swlo[b][slot]=rp&0x3FFu;
      if(((rp>>10)&15u) != (1u<<slot)) T.check=0;           // canonical role
      if(lapply(S,MU[gi]) != (1u<<(10+slot))) T.check=0;    // canonical mask
    }
    for(int i=0;i<4;++i) lo_prev[i]=T.swlo[b][i];
  }
  Lin invF=linverse(S);
  u32 e0=roletrans(invF,er0), e1=roletrans(invF,er1);
  T.erlo[0]=e0&0x3FFu; T.erhi[0]=(e0>>10)&15u;
  T.erlo[1]=e1&0x3FFu; T.erhi[1]=(e1>>10)&15u;
  return T;
}

} // namespace qct

// ---------------- device code ----------------

// packed SU(2): 8 v_pk_fma_f32-class ops per amplitude pair
__device__ __forceinline__ void su2pk(const v2f* __restrict__ G, v2f& p, v2f& q){
  v2f ps = p.yx, qs = q.yx;
  v2f o0 = G[0]*p;
  o0 = __builtin_elementwise_fma(G[1], ps, o0);
  o0 = __builtin_elementwise_fma(G[2], q,  o0);
  o0 = __builtin_elementwise_fma(G[3], qs, o0);
  v2f o1 = G[4]*p;
  o1 = __builtin_elementwise_fma(G[5], ps, o1);
  o1 = __builtin_elementwise_fma(G[6], q,  o1);
  o1 = __builtin_elementwise_fma(G[7], qs, o1);
  p = o0; q = o1;
}

// pre-kernel: expand Rot matrices into pk-friendly {gr,gr},{-gi,gi} pairs
__global__ void gate_kernel(const float* __restrict__ w, float* __restrict__ gws){
  const int t = threadIdx.x;
  if (t < NLAYERS*NQ) {
    const float phi=w[3*t+0], th=w[3*t+1], om=w[3*t+2];
    const float ct=cosf(0.5f*th), stt=sinf(0.5f*th);
    const float aa=0.5f*(phi+om), bb=0.5f*(phi-om);
    const float ca=cosf(aa), sa=sinf(aa);
    const float cb=cosf(bb), sb=sinf(bb);
    const float g0= ca*ct,  g1=-sa*ct;    // u00
    const float g2=-cb*stt, g3=-sb*stt;   // u01
    const float g4= cb*stt, g5=-sb*stt;   // u10
    const float g6= ca*ct,  g7= sa*ct;    // u11
    float* o = gws + 16*t;
    o[0]=g0;  o[1]=g0;  o[2]=-g1; o[3]=g1;
    o[4]=g2;  o[5]=g2;  o[6]=-g3; o[7]=g3;
    o[8]=g4;  o[9]=g4;  o[10]=-g5;o[11]=g5;
    o[12]=g6; o[13]=g6; o[14]=-g7;o[15]=g7;
  }
}

extern "C" __global__ void __launch_bounds__(BLOCK)
qc_kernel(const float* __restrict__ x, const float* __restrict__ gws,
          float* __restrict__ out, const AllTables T){
  extern __shared__ float lds[];
  v2f*   st  = reinterpret_cast<v2f*>(lds);   // 16384 v2f = 128 KiB
  float* enc = lds + 2*NSTATE;                // 28 floats
  float* red = enc + 28;                      // 32 floats

  const unsigned t = threadIdx.x;
  const unsigned s = blockIdx.x;

  if (t < NQ) {
    const float h = x[s*NQ + t] * 1.57079632679489662f;
    enc[2*t]   = cosf(h);
    enc[2*t+1] = sinf(h);
  }
  __syncthreads();

  // --- init: product state, scattered store through W_0 ---
  {
    float pr = 1.0f;
    #pragma unroll
    for (int b = 0; b < 10; ++b) pr *= enc[2*(13-b) + ((t>>b)&1u)];
    u32 a0 = 0;
    #pragma unroll
    for (int j = 0; j < 10; ++j) a0 ^= (0u-((t>>j)&1u)) & T.a0[j];
    #pragma unroll
    for (int i = 0; i < 16; ++i) {
      float vv = pr;
      #pragma unroll
      for (int bq = 0; bq < 4; ++bq) vv *= enc[2*(3-bq) + ((i>>bq)&1)];
      v2f val; val.x = vv; val.y = 0.0f;
      st[a0 ^ T.b0[i]] = val;
    }
  }
  __syncthreads();

  u32 SW = 0;
  v2f v[16];

  // --- passes 0..22 (with stores) ---
  #pragma unroll 1
  for (int k = 0; k < 23; ++k) {
    const int l = k>>2, g = k&3;
    const bool four = (g < 3);
    const int q0 = four ? 4*g : 12;
    const v2f* gp = reinterpret_cast<const v2f*>(gws) + (l*NQ + q0)*8;

    const u32 s0 = (u32)(__popc(t & T.swlo[k][0]) & 1);
    const u32 s1 = (u32)(__popc(t & T.swlo[k][1]) & 1);
    const u32 s2 = (u32)(__popc(t & T.swlo[k][2]) & 1);
    const u32 s3 = (u32)(__popc(t & T.swlo[k][3]) & 1);
    SW = s0 | (s1<<1) | (s2<<2) | (s3<<3);

    const u32 rb = t ^ (SW<<10);
    #pragma unroll
    for (int c = 0; c < 16; ++c) v[c] = st[rb ^ ((u32)c<<10)];

    if (four) {
      #pragma unroll
      for (int i = 0; i < 4; ++i) {
        #pragma unroll
        for (int c = 0; c < 16; ++c)
          if (!(c & (1<<i)))
            su2pk(gp + 8*i, v[c], v[c | (1<<i)]);
      }
    } else {
      #pragma unroll
      for (int c = 0; c < 16; ++c) if (!(c & 4)) su2pk(gp,     v[c], v[c|4]);
      #pragma unroll
      for (int c = 0; c < 16; ++c) if (!(c & 8)) su2pk(gp + 8, v[c], v[c|8]);
    }

    __syncthreads();   // all reads done before any scatter lands

    u32 ab = 0;
    #pragma unroll
    for (int j = 0; j < 10; ++j) ab ^= (0u-((t>>j)&1u)) & T.wA[k][j];
    ab ^= (0u-s0) & T.wB[k][1];
    ab ^= (0u-s1) & T.wB[k][2];
    ab ^= (0u-s2) & T.wB[k][4];
    ab ^= (0u-s3) & T.wB[k][8];
    #pragma unroll
    for (int c = 0; c < 16; ++c) st[ab ^ T.wB[k][c]] = v[c];

    __syncthreads();   // scatter complete before next pass reads
  }

  // --- pass 23 (2-gate) fused with expectation, no store ---
  {
    const int k = 23;
    const v2f* gp = reinterpret_cast<const v2f*>(gws) + (5*NQ + 12)*8;
    const u32 s2 = (u32)(__popc(t & T.swlo[k][2]) & 1);
    const u32 s3 = (u32)(__popc(t & T.swlo[k][3]) & 1);
    SW = (s2<<2) | (s3<<3);
    const u32 rb = t ^ (SW<<10);
    #pragma unroll
    for (int c = 0; c < 16; ++c) v[c] = st[rb ^ ((u32)c<<10)];
    #pragma unroll
    for (int c = 0; c < 16; ++c) if (!(c & 4)) su2pk(gp,     v[c], v[c|4]);
    #pragma unroll
    for (int c = 0; c < 16; ++c) if (!(c & 8)) su2pk(gp + 8, v[c], v[c|8]);
  }

  float z0 = 0.0f, z1 = 0.0f;
  #pragma unroll
  for (int c = 0; c < 16; ++c) {
    const v2f a = v[c];
    const float pr = a.x*a.x + a.y*a.y;
    const bool sg0 = (__popc((u32)c & T.erhi[0]) & 1) != 0;
    const bool sg1 = (__popc((u32)c & T.erhi[1]) & 1) != 0;
    z0 += sg0 ? -pr : pr;
    z1 += sg1 ? -pr : pr;
  }
  {
    const u32 f0 = (u32)((__popc(t & T.erlo[0]) ^ __popc(SW & T.erhi[0])) & 1);
    const u32 f1 = (u32)((__popc(t & T.erlo[1]) ^ __popc(SW & T.erhi[1])) & 1);
    if (f0) z0 = -z0;
    if (f1) z1 = -z1;
  }

  #pragma unroll
  for (int off = 32; off > 0; off >>= 1) {
    z0 += __shfl_down(z0, off, 64);
    z1 += __shfl_down(z1, off, 64);
  }
  if ((t & 63u) == 0u) { red[(t>>6)*2] = z0; red[(t>>6)*2+1] = z1; }
  __syncthreads();
  if (t == 0) {
    float a0 = 0.0f, a1 = 0.0f;
    #pragma unroll
    for (int kk = 0; kk < 16; ++kk) { a0 += red[2*kk]; a1 += red[2*kk+1]; }
    out[2*s]   = a0;
    out[2*s+1] = a1;
  }
}

extern "C" void kernel_launch(void* const* d_in, const int* in_sizes, int n_in,
                              void* d_out, int out_size, void* d_ws, size_t ws_size,
                              hipStream_t stream) {
  const float* x = (const float*)d_in[0];   // (4096, 14) f32
  const float* w = (const float*)d_in[1];   // (6, 14, 3) f32
  float* out = (float*)d_out;               // (4096, 2) f32
  float* gws = (float*)d_ws;                // 84 * 16 floats
  const int B = in_sizes[0] / NQ;

  const AllTables T = qct::make_all();      // ~50 us host work, deterministic

  gate_kernel<<<1, 128, 0, stream>>>(w, gws);

  const size_t lds_bytes = (size_t)(2*NSTATE + 28 + 36) * sizeof(float);
  (void)hipFuncSetAttribute(reinterpret_cast<const void*>(qc_kernel),
                            hipFuncAttributeMaxDynamicSharedMemorySize,
                            (int)lds_bytes);
  qc_kernel<<<B, BLOCK, lds_bytes, stream>>>(x, gws, out, T);
}